// Round 6
// baseline (76.902 us; speedup 1.0000x reference)
//
#include <hip/hip_runtime.h>

// SymmetricPooling: depthwise 5x5 binary-symmetric conv, VALID, stride 1.
// x: (16,128,128,32) f32 -> out: (16,124,124,288) f32, channel order c*9+f,
// f = eta*3 + phi, taps = {eta,4-eta} x {phi,4-phi} (deduped at centre).
//
// R6 = R1 with the LDS transpose + __syncthreads DELETED. A thread's 9
// outputs for fixed (x,c) are contiguous in memory (out[..][x][c*9+..]), so
// each thread stores its own 36B chunk directly: dwordx4 + dwordx4 + dword.
// A wave's 3 back-to-back store instrs fully cover a contiguous 2304B span
// -> L2 write-combines to full 128B lines. Single-variable A/B vs R1:
// removes the barrier's vmcnt(0)-drain from every block's critical path.

#define BB 16
#define HH 128
#define WW 128
#define CC 32
#define OH 124
#define OW 124
#define NF 9
#define OC (CC * NF)   // 288
#define TX 4           // x positions per block
#define NXB (OW / TX)  // 31

// dword-aligned (not 16B) vector stores: out chunks are 36B-strided
typedef float f32x4 __attribute__((ext_vector_type(4), aligned(4)));

__global__ __launch_bounds__(128)
void sympool_kernel(const float* __restrict__ x, float* __restrict__ out) {
    const int t = threadIdx.x;
    const int c = t & 31;        // channel
    const int d = t >> 5;        // 0..3, x offset within tile

    const int blk  = blockIdx.x;
    const int xb   = blk % NXB;
    const int rest = blk / NXB;
    const int y    = rest % OH;
    const int b    = rest / OH;
    const int xx   = xb * TX + d;

    // Lanes 0..31 = channels (contiguous 128B), lanes 32..63 = next x ->
    // each global_load_dword is one contiguous 256B wave transaction.
    const float* p = x + ((size_t)((b * HH + y) * WW + xx)) * CC + c;
    float v[5][5];
#pragma unroll
    for (int i = 0; i < 5; ++i) {
#pragma unroll
        for (int j = 0; j < 5; ++j) {
            v[i][j] = p[(i * WW + j) * CC];
        }
    }

    // Row sums: R[eta][j] = sum over i in {eta, 4-eta} (dedup) of v[i][j]
    float R[3][5];
#pragma unroll
    for (int j = 0; j < 5; ++j) {
        R[0][j] = v[0][j] + v[4][j];
        R[1][j] = v[1][j] + v[3][j];
        R[2][j] = v[2][j];
    }

    // 9 outputs, f = eta*3 + phi — contiguous 36B at out[...][xx][c*9]
    float o[9];
#pragma unroll
    for (int e = 0; e < 3; ++e) {
        o[e * 3 + 0] = R[e][0] + R[e][4];
        o[e * 3 + 1] = R[e][1] + R[e][3];
        o[e * 3 + 2] = R[e][2];
    }

    float* dst = out + ((size_t)((b * OH + y) * OW + xx)) * OC + c * NF;
    *(f32x4*)(dst + 0) = *(const f32x4*)(o + 0);
    *(f32x4*)(dst + 4) = *(const f32x4*)(o + 4);
    dst[8] = o[8];
}

extern "C" void kernel_launch(void* const* d_in, const int* in_sizes, int n_in,
                              void* d_out, int out_size, void* d_ws, size_t ws_size,
                              hipStream_t stream) {
    const float* x = (const float*)d_in[0];
    // d_in[1] is the binary symmetric kernel; its structure is hardcoded.
    float* out = (float*)d_out;

    const int grid = BB * OH * NXB;  // 16*124*31 = 61504
    sympool_kernel<<<grid, 128, 0, stream>>>(x, out);
}

// Round 7
// 46.905 us; speedup vs baseline: 1.6395x; 1.6395x over previous
//
#include <hip/hip_runtime.h>

// SymmetricPooling: depthwise 5x5 binary-symmetric conv, VALID, stride 1.
// x: (16,128,128,32) f32 -> out: (16,124,124,288) f32, channel order c*9+f,
// f = eta*3 + phi, taps = {eta,4-eta} x {phi,4-phi} (deduped at centre).
//
// R7 = R5 (best: 71.6us; LDS transpose + nt float4 stores) + ONE change:
// bijective chunked XCD swizzle. Dispatch round-robins block ids over 8 XCDs,
// so with linear id->address mapping each XCD's L2 writeback stream is 4.5KB
// chunks with 36KB holes -> DRAM row thrash. Chunked swizzle gives XCD k one
// contiguous 35MB output region swept linearly (8 dense streams), and its
// input slice (~4.2MB) fits the XCD-private 4MiB L2.

#define BB 16
#define HH 128
#define WW 128
#define CC 32
#define OH 124
#define OW 124
#define NF 9
#define OC (CC * NF)   // 288
#define TX 4           // x positions per block
#define NXB (OW / TX)  // 31
#define NWG (BB * OH * NXB)  // 61504 = 8 * 7688

typedef float f32x4 __attribute__((ext_vector_type(4)));

__global__ __launch_bounds__(128)
void sympool_kernel(const float* __restrict__ x, float* __restrict__ out) {
    __shared__ float tile[TX * OC];  // 1152 floats = 4.5 KB

    const int t = threadIdx.x;
    const int c = t & 31;        // channel
    const int d = t >> 5;        // 0..3, x offset within tile

    // chunked XCD swizzle: XCD (wg%8) sweeps contiguous region (wg%8) linearly
    const int wg   = blockIdx.x;
    const int blk  = (wg & 7) * (NWG / 8) + (wg >> 3);

    const int xb   = blk % NXB;
    const int rest = blk / NXB;
    const int y    = rest % OH;
    const int b    = rest / OH;
    const int x0   = xb * TX;
    const int xx   = x0 + d;

    // Lanes 0..31 = channels (contiguous 128B), lanes 32..63 = next x ->
    // each global_load_dword is one contiguous 256B wave transaction.
    const float* p = x + ((size_t)((b * HH + y) * WW + xx)) * CC + c;
    float v[5][5];
#pragma unroll
    for (int i = 0; i < 5; ++i) {
#pragma unroll
        for (int j = 0; j < 5; ++j) {
            v[i][j] = p[(i * WW + j) * CC];
        }
    }

    // Row sums: R[eta][j] = sum over i in {eta, 4-eta} (dedup) of v[i][j]
    float R[3][5];
#pragma unroll
    for (int j = 0; j < 5; ++j) {
        R[0][j] = v[0][j] + v[4][j];
        R[1][j] = v[1][j] + v[3][j];
        R[2][j] = v[2][j];
    }

    // Column sums -> 9 outputs, f = eta*3 + phi (LDS write: stride-9 dwords,
    // 9 coprime 32 -> bank-conflict-free)
    float* dst = &tile[d * OC + c * NF];
#pragma unroll
    for (int e = 0; e < 3; ++e) {
        dst[e * 3 + 0] = R[e][0] + R[e][4];
        dst[e * 3 + 1] = R[e][1] + R[e][3];
        dst[e * 3 + 2] = R[e][2];
    }

    __syncthreads();

    // Stream the 4x288-float tile out as aligned dwordx4, nontemporal.
    f32x4* outv = (f32x4*)(out + ((size_t)((b * OH + y) * OW + x0)) * OC);
    const f32x4* tv = (const f32x4*)tile;
    const int nvec = TX * OC / 4;  // 288
#pragma unroll
    for (int k = 0; k < 3; ++k) {
        int idx = t + k * 128;
        if (idx < nvec) __builtin_nontemporal_store(tv[idx], &outv[idx]);
    }
}

extern "C" void kernel_launch(void* const* d_in, const int* in_sizes, int n_in,
                              void* d_out, int out_size, void* d_ws, size_t ws_size,
                              hipStream_t stream) {
    const float* x = (const float*)d_in[0];
    // d_in[1] is the binary symmetric kernel; its structure is hardcoded.
    float* out = (float*)d_out;

    sympool_kernel<<<NWG, 128, 0, stream>>>(x, out);
}